// Round 5
// baseline (1034.439 us; speedup 1.0000x reference)
//
#include <hip/hip_runtime.h>
#include <math.h>

// ---------------------------------------------------------------------------
// CommunityTrustGNN: 2-layer GraphSAGE (mean agg) + trust MLP head
// N=100000 nodes, E=1600000 edges, dims 64 -> 64 -> 32 -> (16 -> 1)
//
// Round 16: edge-centric LDS-atomic aggregation (both layers).
//  * k_m2: CSR build/persist + serial walk + shfl trees DELETED. Edges
//    streamed: 32-lane groups read one 128B u16b row, unpack, 2x ds_add_f32
//    into acc[64][65] fp32 accumulators (stride 65 -> mixed-parity banks).
//    ~6 wave-instrs/edge vs ~27 measured in round-15 (VALUBusy 60%).
//    Finalize -> packhl -> sHu (LDS reused) -> Phase B split-bf16 MFMA
//    (round-15 verbatim). adjG/nodeOff no longer written.
//  * k_a2: same edge-centric structure on P16b (16-lane groups, 64B rows,
//    acc[64][33]); trust head 8 threads/node from LDS h. pairs re-read
//    instead of adj (CSR deleted).
//  * k_m1, k_w: round-15 verbatim.
// ---------------------------------------------------------------------------

#define NBUCK   1563     // ceil(100000/64) buckets of 64 dst nodes
#define BCAP    1536     // bucket capacity (mean 1024, +16 sigma)
#define BKCHUNK 4096     // edges per bucket-chunk block in M1

typedef __attribute__((ext_vector_type(8))) __bf16 bf16x8;
typedef __attribute__((ext_vector_type(4))) float  f32x4;

union BU { bf16x8 v; unsigned short u[8]; };

// bf16 helpers (round-to-nearest-even pack, exact unpack)
__device__ inline unsigned short f2bf(float x) {
    unsigned u = __float_as_uint(x);
    unsigned r = u + 0x7fffu + ((u >> 16) & 1u);
    return (unsigned short)(r >> 16);
}
__device__ inline float bflo(unsigned u) { return __uint_as_float(u << 16); }
__device__ inline float bfhi(unsigned u) { return __uint_as_float(u & 0xffff0000u); }
__device__ inline float bf2f(unsigned short h) { return __uint_as_float((unsigned)h << 16); }
// pack value as (bf16hi | bf16lo<<16) for split-bf16 A-fragments
__device__ inline unsigned packhl(float x) {
    unsigned short h = f2bf(x);
    unsigned short l = f2bf(x - bf2f(h));
    return (unsigned)h | ((unsigned)l << 16);
}

// --- W: precompute fragment-ordered bf16 hi/lo weight planes ----------------
// gemm1 frags q=(pass*4+nf)*2+kf (16): planes 2q/2q+1, 512 ushorts each.
// gemm2 frags q2=ntile*2+kf (8) at plane offset 32: cols = concat(Wl2,Wr2).
// Lane l of a frag: col = ntile*16+(l&15), k = kf*32+(l>>4)*8+e.
__global__ __launch_bounds__(256) void k_w(
    const float* __restrict__ Wl1, const float* __restrict__ Wr1,
    const float* __restrict__ Wl2, const float* __restrict__ Wr2,
    unsigned short* __restrict__ Wf)
{
    int tid = threadIdx.x;
    for (int idx = tid; idx < 1536; idx += 256) {
        unsigned short hi8[8], lo8[8];
        int base;
        if (idx < 1024) {
            int q = idx >> 6;                 // 0..15: (pass,nf,kf)
            int l = idx & 63;
            int pass = q >> 3, nf = (q >> 1) & 3, kf = q & 1;
            const float* W = pass ? Wr1 : Wl1;
            int col  = nf * 16 + (l & 15);
            int krow = kf * 32 + (l >> 4) * 8;
            #pragma unroll
            for (int e = 0; e < 8; ++e) {
                float w = W[(krow + e) * 64 + col];
                unsigned short h = f2bf(w);
                hi8[e] = h;
                lo8[e] = f2bf(w - bf2f(h));
            }
            base = (q * 2) * 512 + l * 8;
        } else {
            int i2 = idx - 1024;
            int q2 = i2 >> 6;                 // 0..7: (ntile,kf)
            int l = i2 & 63;
            int ntile = q2 >> 1, kf = q2 & 1;
            int col  = ntile * 16 + (l & 15); // 0..63 over concat(Wl2,Wr2)
            const float* W = (col < 32) ? Wl2 : Wr2;
            int c = col & 31;
            int krow = kf * 32 + (l >> 4) * 8;
            #pragma unroll
            for (int e = 0; e < 8; ++e) {
                float w = W[(krow + e) * 32 + c];
                unsigned short h = f2bf(w);
                hi8[e] = h;
                lo8[e] = f2bf(w - bf2f(h));
            }
            base = (32 + q2 * 2) * 512 + l * 8;
        }
        #pragma unroll
        for (int e = 0; e < 8; ++e) {
            Wf[base + e]       = hi8[e];
            Wf[base + 512 + e] = lo8[e];
        }
    }
}

// --- M1: interleaved gemm1 tiles + bucket-scatter chunks --------------------
// blockIdx%5==4 -> bucket chunk (blockIdx/5); else gemm tile 4*(b/5)+(b%5).
// gemm1 (MFMA): u(bf16) = x@Wl1 ; v(f32) = x@Wr1 + b1, split-bf16 3-term.
// bucket: edges -> packed (src | local_dst<<17), grouped by dst>>6
__global__ __launch_bounds__(256) void k_m1(
    const float* __restrict__ x,
    const unsigned short* __restrict__ Wf, const float* __restrict__ b1,
    unsigned* __restrict__ u16b, float* __restrict__ v,
    const int* __restrict__ src, const int* __restrict__ dst,
    int* __restrict__ gcnt, unsigned* __restrict__ pairs,
    int N, int E, int GB, int BKB)
{
    __shared__ int hist[NBUCK];           // 6252B (scatter blocks only)
    int tid = threadIdx.x;
    int g = blockIdx.x / 5, r5 = blockIdx.x % 5;

    if (r5 == 4) {
        // ---------------- bucket-scatter path ----------------
        if (g >= BKB) return;
        int e0 = g * BKCHUNK;
        int e1 = min(e0 + BKCHUNK, E);

        for (int i = tid; i < NBUCK; i += 256) hist[i] = 0;
        __syncthreads();
        for (int e = e0 + tid; e < e1; e += 256)
            atomicAdd(&hist[((unsigned)dst[e]) >> 6], 1);
        __syncthreads();
        // pipelined reservation: 7 independent atomics issued back-to-back
        int cnt[7], base[7];
        #pragma unroll
        for (int t = 0; t < 7; ++t) {
            int i = tid + t * 256;
            cnt[t] = (i < NBUCK) ? hist[i] : 0;
        }
        #pragma unroll
        for (int t = 0; t < 7; ++t) {
            int i = tid + t * 256;
            base[t] = (i < NBUCK) ? atomicAdd(&gcnt[i], cnt[t]) : 0;
        }
        #pragma unroll
        for (int t = 0; t < 7; ++t) {
            int i = tid + t * 256;
            if (i < NBUCK) hist[i] = i * BCAP + base[t];
        }
        __syncthreads();
        for (int e = e0 + tid; e < e1; e += 256) {
            int t = dst[e];
            int b = ((unsigned)t) >> 6;
            int pos = atomicAdd(&hist[b], 1);
            if (pos < (b + 1) * BCAP)   // overflow clamp (16-sigma margin)
                pairs[pos] = (unsigned)src[e] | ((unsigned)(t & 63) << 17);
        }
        return;
    }

    // ---------------- gemm1 path: split-bf16 MFMA, no LDS -----------------
    int tile = 4 * g + r5;
    if (tile >= GB) return;
    int nblk = tile * 64;

    int l  = tid & 63, wv = tid >> 6;   // lane, wave(0..3)
    int la = l & 15,   g4 = l >> 4;     // col-within-16, k-group
    int arow = nblk + wv * 16 + la;     // A row for this lane
    bool rowOK = (arow < N);

    // A fragments from global (16 rows x 128B contiguous per k-half)
    BU ahi[2], alo[2];
    #pragma unroll
    for (int kf = 0; kf < 2; ++kf) {
        float xv[8];
        if (rowOK) {
            const float* xp = &x[(size_t)arow * 64 + kf * 32 + g4 * 8];
            float4 p0 = *(const float4*)xp;
            float4 p1 = *(const float4*)(xp + 4);
            xv[0] = p0.x; xv[1] = p0.y; xv[2] = p0.z; xv[3] = p0.w;
            xv[4] = p1.x; xv[5] = p1.y; xv[6] = p1.z; xv[7] = p1.w;
        } else {
            #pragma unroll
            for (int e = 0; e < 8; ++e) xv[e] = 0.0f;
        }
        #pragma unroll
        for (int e = 0; e < 8; ++e) {
            unsigned short h = f2bf(xv[e]);
            ahi[kf].u[e] = h;
            alo[kf].u[e] = f2bf(xv[e] - bf2f(h));
        }
    }

    unsigned short* u16 = (unsigned short*)u16b;

    #pragma unroll
    for (int pass = 0; pass < 2; ++pass) {
        #pragma unroll
        for (int nf = 0; nf < 4; ++nf) {
            int n0 = nf * 16;
            f32x4 acc = {0.f, 0.f, 0.f, 0.f};
            #pragma unroll
            for (int kf = 0; kf < 2; ++kf) {
                int q2 = ((pass * 4 + nf) * 2 + kf) * 2;
                bf16x8 bhi = *(const bf16x8*)&Wf[(q2 + 0) * 512 + l * 8];
                bf16x8 blo = *(const bf16x8*)&Wf[(q2 + 1) * 512 + l * 8];
                acc = __builtin_amdgcn_mfma_f32_16x16x32_bf16(ahi[kf].v, bhi, acc, 0, 0, 0);
                acc = __builtin_amdgcn_mfma_f32_16x16x32_bf16(alo[kf].v, bhi, acc, 0, 0, 0);
                acc = __builtin_amdgcn_mfma_f32_16x16x32_bf16(ahi[kf].v, blo, acc, 0, 0, 0);
            }
            // D: col = la, row = g4*4 + r  (m89-verified layout)
            if (pass == 0) {
                #pragma unroll
                for (int rr = 0; rr < 4; ++rr) {
                    int nd = nblk + wv * 16 + g4 * 4 + rr;
                    if (nd < N)
                        u16[(size_t)nd * 64 + n0 + la] = f2bf(acc[rr]);
                }
            } else {
                float bb = b1[n0 + la];
                #pragma unroll
                for (int rr = 0; rr < 4; ++rr) {
                    int nd = nblk + wv * 16 + g4 * 4 + rr;
                    if (nd < N)
                        v[(size_t)nd * 64 + n0 + la] = acc[rr] + bb;
                }
            }
        }
    }
}

// --- M2: edge-centric agg1 (LDS fp32 atomics) + gemm2 (MFMA). ---------------
// Block = 64-node bucket, 512 threads. 16 groups x 32 lanes stream edges:
// one 128B u16b row per group-instr, 2x ds_add_f32 into acc[64][65].
// Finalize -> relu -> packhl -> sHu (LDS reused) -> Phase B MFMA.
__global__ __launch_bounds__(512) void k_m2(
    const unsigned* __restrict__ pairs, const int* __restrict__ gcnt,
    const unsigned* __restrict__ u16b, const float* __restrict__ v,
    const unsigned short* __restrict__ Wf, const float* __restrict__ b2,
    unsigned* __restrict__ P16b, float* __restrict__ Qout, int N)
{
    __shared__ __align__(16) char smem[64 * 76 * 4]; // acc 64x65 f32, then sHu 64x76 u32
    __shared__ int sDeg[64];
    float* acc = (float*)smem;
    unsigned* sHu = (unsigned*)smem;

    int tid = threadIdx.x;
    int b = blockIdx.x;
    int nodeBase = b * 64;
    int count = min(gcnt[b], BCAP);
    const unsigned* pp = pairs + (size_t)b * BCAP;

    for (int i = tid; i < 64 * 65; i += 512) acc[i] = 0.0f;
    if (tid < 64) sDeg[tid] = 0;
    __syncthreads();

    // ---- edge-centric accumulate ----
    int grp = tid >> 5, lane = tid & 31;
    for (int j = grp; j < count; j += 16) {
        unsigned e = pp[j];
        int s  = e & 0x1FFFF;
        int ld = (e >> 17) & 63;
        unsigned w = u16b[(size_t)s * 32 + lane];
        atomicAdd(&acc[ld * 65 + 2 * lane],     bflo(w));
        atomicAdd(&acc[ld * 65 + 2 * lane + 1], bfhi(w));
        if (lane == 0) atomicAdd(&sDeg[ld], 1);
    }
    __syncthreads();

    // ---- finalize: 8 threads/node x 8 feats -> regs ----
    int node_l = tid >> 3, j8 = tid & 7;
    int node = nodeBase + node_l;
    int f0 = j8 * 8;
    float h[8];
    {
        int deg = sDeg[node_l];
        float invd = (deg > 0) ? 1.0f / (float)deg : 1.0f;
        #pragma unroll
        for (int e = 0; e < 8; ++e) h[e] = acc[node_l * 65 + f0 + e];
        if (node < N) {
            float4 v0 = *(const float4*)&v[(size_t)node * 64 + f0];
            float4 v1 = *(const float4*)&v[(size_t)node * 64 + f0 + 4];
            h[0] = fmaxf(h[0] * invd + v0.x, 0.0f);
            h[1] = fmaxf(h[1] * invd + v0.y, 0.0f);
            h[2] = fmaxf(h[2] * invd + v0.z, 0.0f);
            h[3] = fmaxf(h[3] * invd + v0.w, 0.0f);
            h[4] = fmaxf(h[4] * invd + v1.x, 0.0f);
            h[5] = fmaxf(h[5] * invd + v1.y, 0.0f);
            h[6] = fmaxf(h[6] * invd + v1.z, 0.0f);
            h[7] = fmaxf(h[7] * invd + v1.w, 0.0f);
        } else {
            #pragma unroll
            for (int e = 0; e < 8; ++e) h[e] = 0.0f;
        }
    }
    __syncthreads();   // all acc reads complete before sHu overwrite
    {
        uint4 o0 = make_uint4(packhl(h[0]), packhl(h[1]), packhl(h[2]), packhl(h[3]));
        uint4 o1 = make_uint4(packhl(h[4]), packhl(h[5]), packhl(h[6]), packhl(h[7]));
        *(uint4*)&sHu[node_l * 76 + f0]     = o0;
        *(uint4*)&sHu[node_l * 76 + f0 + 4] = o1;
    }
    __syncthreads();

    // ---- Phase B: 64x64 split-bf16 MFMA (8 waves x 2 n-tiles) ----
    int w = tid >> 6, l = tid & 63;
    int la = l & 15, g4 = l >> 4;
    int mtile = w & 3, nt2 = (w >> 2) * 2;   // n-tiles nt2, nt2+1

    BU ahi[2], alo[2];
    #pragma unroll
    for (int kf = 0; kf < 2; ++kf) {
        const unsigned* hp = &sHu[(mtile * 16 + la) * 76 + kf * 32 + g4 * 8];
        uint4 a0 = *(const uint4*)hp;
        uint4 a1 = *(const uint4*)(hp + 4);
        unsigned wv8[8] = {a0.x, a0.y, a0.z, a0.w, a1.x, a1.y, a1.z, a1.w};
        #pragma unroll
        for (int e = 0; e < 8; ++e) {
            ahi[kf].u[e] = (unsigned short)wv8[e];
            alo[kf].u[e] = (unsigned short)(wv8[e] >> 16);
        }
    }

    unsigned short* Pus = (unsigned short*)P16b;
    #pragma unroll
    for (int j = 0; j < 2; ++j) {
        int ntile = nt2 + j;
        f32x4 ac = {0.f, 0.f, 0.f, 0.f};
        #pragma unroll
        for (int kf = 0; kf < 2; ++kf) {
            const unsigned short* Wq = Wf + (size_t)(32 + (ntile * 2 + kf) * 2) * 512;
            bf16x8 bhi = *(const bf16x8*)&Wq[l * 8];
            bf16x8 blo = *(const bf16x8*)&Wq[512 + l * 8];
            ac = __builtin_amdgcn_mfma_f32_16x16x32_bf16(ahi[kf].v, bhi, ac, 0, 0, 0);
            ac = __builtin_amdgcn_mfma_f32_16x16x32_bf16(alo[kf].v, bhi, ac, 0, 0, 0);
            ac = __builtin_amdgcn_mfma_f32_16x16x32_bf16(ahi[kf].v, blo, ac, 0, 0, 0);
        }
        int col = ntile * 16 + la;
        if (col < 32) {
            #pragma unroll
            for (int rr = 0; rr < 4; ++rr) {
                int nd = nodeBase + mtile * 16 + g4 * 4 + rr;
                if (nd < N)
                    Pus[(size_t)nd * 32 + col] = f2bf(ac[rr]);
            }
        } else {
            float bb = b2[col - 32];
            #pragma unroll
            for (int rr = 0; rr < 4; ++rr) {
                int nd = nodeBase + mtile * 16 + g4 * 4 + rr;
                if (nd < N)
                    Qout[(size_t)nd * 32 + (col - 32)] = ac[rr] + bb;
            }
        }
    }
}

// --- A2: edge-centric agg2 (LDS fp32 atomics) + trust head. -----------------
// Block = 64-node bucket, 512 threads. 32 groups x 16 lanes stream edges:
// one 64B P16b row per group-instr, 2x ds_add_f32 into acc[64][33].
// Finalize: out_h = acc*invd + Q (h kept in LDS); head: 8 threads/node.
__global__ __launch_bounds__(512) void k_a2(
    const unsigned* __restrict__ pairs, const int* __restrict__ gcnt,
    const unsigned* __restrict__ P16b, const float* __restrict__ Q,
    const float* __restrict__ Wt1, const float* __restrict__ bt1,
    const float* __restrict__ Wt2, const float* __restrict__ bt2,
    float* __restrict__ out_h, float* __restrict__ out_trust, int N)
{
    __shared__ float accA[64 * 33];   // 8448B
    __shared__ int   sDegA[64];
    __shared__ float sWt1[32 * 16];
    __shared__ float sWt2[16];

    int tid = threadIdx.x;
    int b = blockIdx.x;
    int nodeBase = b * 64;
    int count = min(gcnt[b], BCAP);
    const unsigned* pp = pairs + (size_t)b * BCAP;

    for (int i = tid; i < 512; i += 512) sWt1[i] = Wt1[i];
    if (tid < 16) sWt2[tid] = Wt2[tid];
    for (int i = tid; i < 64 * 33; i += 512) accA[i] = 0.0f;
    if (tid < 64) sDegA[tid] = 0;
    __syncthreads();

    // ---- edge-centric accumulate ----
    int grp = tid >> 4, lane = tid & 15;
    for (int j = grp; j < count; j += 32) {
        unsigned e = pp[j];
        int s  = e & 0x1FFFF;
        int ld = (e >> 17) & 63;
        unsigned w = P16b[(size_t)s * 16 + lane];
        atomicAdd(&accA[ld * 33 + 2 * lane],     bflo(w));
        atomicAdd(&accA[ld * 33 + 2 * lane + 1], bfhi(w));
        if (lane == 0) atomicAdd(&sDegA[ld], 1);
    }
    __syncthreads();

    // ---- finalize: 8 threads/node x 4 feats; h back into accA in place ----
    int node_l = tid >> 3, j8 = tid & 7;
    int node = nodeBase + node_l;
    int f0 = j8 * 4;
    {
        int deg = sDegA[node_l];
        float invd = (deg > 0) ? 1.0f / (float)deg : 1.0f;
        float hh[4];
        #pragma unroll
        for (int e = 0; e < 4; ++e) hh[e] = accA[node_l * 33 + f0 + e] * invd;
        if (node < N) {
            float4 q4 = *(const float4*)&Q[(size_t)node * 32 + f0];
            hh[0] += q4.x; hh[1] += q4.y; hh[2] += q4.z; hh[3] += q4.w;
            *(float4*)&out_h[(size_t)node * 32 + f0] =
                make_float4(hh[0], hh[1], hh[2], hh[3]);
        }
        #pragma unroll
        for (int e = 0; e < 4; ++e) accA[node_l * 33 + f0 + e] = hh[e];
    }
    __syncthreads();

    // ---- trust head: 8 threads/node, cols 2*j8 and 2*j8+1 ----
    const float* hr = &accA[node_l * 33];
    float ta = bt1[2 * j8], tb = bt1[2 * j8 + 1];
    #pragma unroll 8
    for (int k = 0; k < 32; ++k) {
        float hv = hr[k];
        ta = fmaf(hv, sWt1[k * 16 + 2 * j8],     ta);
        tb = fmaf(hv, sWt1[k * 16 + 2 * j8 + 1], tb);
    }
    ta = fmaxf(ta, 0.0f);
    tb = fmaxf(tb, 0.0f);
    float z = ta * sWt2[2 * j8] + tb * sWt2[2 * j8 + 1];
    z += __shfl_xor(z, 1);
    z += __shfl_xor(z, 2);
    z += __shfl_xor(z, 4);
    if (j8 == 0 && node < N)
        out_trust[node] = 1.0f / (1.0f + expf(-(z + bt2[0])));
}

// ---------------------------------------------------------------------------

extern "C" void kernel_launch(void* const* d_in, const int* in_sizes, int n_in,
                              void* d_out, int out_size, void* d_ws, size_t ws_size,
                              hipStream_t stream)
{
    const float* x   = (const float*)d_in[0];
    const int*   ei  = (const int*)d_in[1];
    const float* Wl1 = (const float*)d_in[2];
    const float* Wr1 = (const float*)d_in[3];
    const float* b1  = (const float*)d_in[4];
    const float* Wl2 = (const float*)d_in[5];
    const float* Wr2 = (const float*)d_in[6];
    const float* b2  = (const float*)d_in[7];
    const float* Wt1 = (const float*)d_in[8];
    const float* bt1 = (const float*)d_in[9];
    const float* Wt2 = (const float*)d_in[10];
    const float* bt2 = (const float*)d_in[11];

    const int N = in_sizes[0] / 64;   // 100000
    const int E = in_sizes[1] / 2;    // 1600000
    const int* src = ei;
    const int* dst = ei + E;

    // Workspace layout (all segments 64B-aligned)
    unsigned* pairs  = (unsigned*)d_ws;                        // NBUCK*BCAP (~9.6MB)
    unsigned* u16b   = pairs + (size_t)NBUCK * BCAP;           // N*32 (bf16 x2)
    float*    v      = (float*)(u16b + (size_t)N * 32);        // N*64
    unsigned* P16b   = (unsigned*)(v + (size_t)N * 64);        // N*16 (bf16 x2)
    float*    Q      = (float*)(P16b + (size_t)N * 16);        // N*32
    int2*     nodeOff= (int2*)(Q + (size_t)N * 32);            // N (unused, layout keep)
    int*      adj    = (int*)(nodeOff + N);                    // NBUCK*BCAP (unused)
    int*      gcnt   = adj + (size_t)NBUCK * BCAP;             // 2048 (1563 used)
    unsigned short* Wf = (unsigned short*)(gcnt + 2048);       // 48 planes x 512
    (void)nodeOff; (void)adj;
    // total ~78 MB

    hipMemsetAsync(gcnt, 0, 2048 * sizeof(int), stream);

    k_w<<<1, 256, 0, stream>>>(Wl1, Wr1, Wl2, Wr2, Wf);

    const int GB  = (N + 63) / 64;               // 1563 gemm1 tiles
    const int BKB = (E + BKCHUNK - 1) / BKCHUNK; // 391 bucket chunks
    int grp = (GB + 3) / 4 > BKB ? (GB + 3) / 4 : BKB;   // 391
    k_m1<<<5 * grp, 256, 0, stream>>>(x, Wf, b1, u16b, v,
                                      src, dst, gcnt, pairs, N, E, GB, BKB);
    k_m2<<<NBUCK, 512, 0, stream>>>(pairs, gcnt, u16b, v, Wf, b2,
                                    P16b, Q, N);

    float* out_h     = (float*)d_out;
    float* out_trust = out_h + (size_t)N * 32;
    k_a2<<<NBUCK, 512, 0, stream>>>(pairs, gcnt, P16b, Q,
                                    Wt1, bt1, Wt2, bt2,
                                    out_h, out_trust, N);
}

// Round 6
// 219.639 us; speedup vs baseline: 4.7097x; 4.7097x over previous
//
#include <hip/hip_runtime.h>
#include <math.h>

// ---------------------------------------------------------------------------
// CommunityTrustGNN: 2-layer GraphSAGE (mean agg) + trust MLP head
// N=100000 nodes, E=1600000 edges, dims 64 -> 64 -> 32 -> (16 -> 1)
//
// Round 17 = best harness-verified piece per kernel (round-16's edge-centric
// LDS-atomic aggregation hit the LDS-atomic serialization wall: ~200M
// ds_add_f32 RMW ops -> 603us with all pipes idle. LDS float atomics
// serialize at ~1-2cy/op: never on the per-edge path.)
//  * k_w:  round-14 (gemm1 + gemm2 fragment planes).
//  * k_m1: round-15 (no-LDS split-bf16 MFMA gemm1 + 4096-edge scatter,
//          pipelined reservation). Measured 60-61us twice.
//  * k_m2: round-14 (CSR build+persist, serial-walk Phase A -> packed sHu,
//          split-bf16 MFMA Phase B, LDS 26624B). Harness-verified round 3.
//  * k_a2: round-8 (adj/nodeOff walk, 16 lanes/node, shfl MLP head).
// ---------------------------------------------------------------------------

#define NBUCK   1563     // ceil(100000/64) buckets of 64 dst nodes
#define BCAP    1536     // bucket capacity (mean 1024, +16 sigma)
#define BKCHUNK 4096     // edges per bucket-chunk block in M1

typedef __attribute__((ext_vector_type(8))) __bf16 bf16x8;
typedef __attribute__((ext_vector_type(4))) float  f32x4;

union BU { bf16x8 v; unsigned short u[8]; };

// bf16 helpers (round-to-nearest-even pack, exact unpack)
__device__ inline unsigned short f2bf(float x) {
    unsigned u = __float_as_uint(x);
    unsigned r = u + 0x7fffu + ((u >> 16) & 1u);
    return (unsigned short)(r >> 16);
}
__device__ inline float bflo(unsigned u) { return __uint_as_float(u << 16); }
__device__ inline float bfhi(unsigned u) { return __uint_as_float(u & 0xffff0000u); }
__device__ inline float bf2f(unsigned short h) { return __uint_as_float((unsigned)h << 16); }
// pack value as (bf16hi | bf16lo<<16) for split-bf16 A-fragments
__device__ inline unsigned packhl(float x) {
    unsigned short h = f2bf(x);
    unsigned short l = f2bf(x - bf2f(h));
    return (unsigned)h | ((unsigned)l << 16);
}

// --- W: precompute fragment-ordered bf16 hi/lo weight planes ----------------
// gemm1 frags q=(pass*4+nf)*2+kf (16): planes 2q/2q+1, 512 ushorts each.
// gemm2 frags q2=ntile*2+kf (8) at plane offset 32: cols = concat(Wl2,Wr2).
// Lane l of a frag: col = ntile*16+(l&15), k = kf*32+(l>>4)*8+e.
__global__ __launch_bounds__(256) void k_w(
    const float* __restrict__ Wl1, const float* __restrict__ Wr1,
    const float* __restrict__ Wl2, const float* __restrict__ Wr2,
    unsigned short* __restrict__ Wf)
{
    int tid = threadIdx.x;
    for (int idx = tid; idx < 1536; idx += 256) {
        unsigned short hi8[8], lo8[8];
        int base;
        if (idx < 1024) {
            int q = idx >> 6;                 // 0..15: (pass,nf,kf)
            int l = idx & 63;
            int pass = q >> 3, nf = (q >> 1) & 3, kf = q & 1;
            const float* W = pass ? Wr1 : Wl1;
            int col  = nf * 16 + (l & 15);
            int krow = kf * 32 + (l >> 4) * 8;
            #pragma unroll
            for (int e = 0; e < 8; ++e) {
                float w = W[(krow + e) * 64 + col];
                unsigned short h = f2bf(w);
                hi8[e] = h;
                lo8[e] = f2bf(w - bf2f(h));
            }
            base = (q * 2) * 512 + l * 8;
        } else {
            int i2 = idx - 1024;
            int q2 = i2 >> 6;                 // 0..7: (ntile,kf)
            int l = i2 & 63;
            int ntile = q2 >> 1, kf = q2 & 1;
            int col  = ntile * 16 + (l & 15); // 0..63 over concat(Wl2,Wr2)
            const float* W = (col < 32) ? Wl2 : Wr2;
            int c = col & 31;
            int krow = kf * 32 + (l >> 4) * 8;
            #pragma unroll
            for (int e = 0; e < 8; ++e) {
                float w = W[(krow + e) * 32 + c];
                unsigned short h = f2bf(w);
                hi8[e] = h;
                lo8[e] = f2bf(w - bf2f(h));
            }
            base = (32 + q2 * 2) * 512 + l * 8;
        }
        #pragma unroll
        for (int e = 0; e < 8; ++e) {
            Wf[base + e]       = hi8[e];
            Wf[base + 512 + e] = lo8[e];
        }
    }
}

// --- M1: interleaved gemm1 tiles + bucket-scatter chunks --------------------
// blockIdx%5==4 -> bucket chunk (blockIdx/5); else gemm tile 4*(b/5)+(b%5).
// gemm1 (MFMA): u(bf16) = x@Wl1 ; v(f32) = x@Wr1 + b1, split-bf16 3-term.
// bucket: edges -> packed (src | local_dst<<17), grouped by dst>>6
__global__ __launch_bounds__(256) void k_m1(
    const float* __restrict__ x,
    const unsigned short* __restrict__ Wf, const float* __restrict__ b1,
    unsigned* __restrict__ u16b, float* __restrict__ v,
    const int* __restrict__ src, const int* __restrict__ dst,
    int* __restrict__ gcnt, unsigned* __restrict__ pairs,
    int N, int E, int GB, int BKB)
{
    __shared__ int hist[NBUCK];           // 6252B (scatter blocks only)
    int tid = threadIdx.x;
    int g = blockIdx.x / 5, r5 = blockIdx.x % 5;

    if (r5 == 4) {
        // ---------------- bucket-scatter path ----------------
        if (g >= BKB) return;
        int e0 = g * BKCHUNK;
        int e1 = min(e0 + BKCHUNK, E);

        for (int i = tid; i < NBUCK; i += 256) hist[i] = 0;
        __syncthreads();
        for (int e = e0 + tid; e < e1; e += 256)
            atomicAdd(&hist[((unsigned)dst[e]) >> 6], 1);
        __syncthreads();
        // pipelined reservation: 7 independent atomics issued back-to-back
        int cnt[7], base[7];
        #pragma unroll
        for (int t = 0; t < 7; ++t) {
            int i = tid + t * 256;
            cnt[t] = (i < NBUCK) ? hist[i] : 0;
        }
        #pragma unroll
        for (int t = 0; t < 7; ++t) {
            int i = tid + t * 256;
            base[t] = (i < NBUCK) ? atomicAdd(&gcnt[i], cnt[t]) : 0;
        }
        #pragma unroll
        for (int t = 0; t < 7; ++t) {
            int i = tid + t * 256;
            if (i < NBUCK) hist[i] = i * BCAP + base[t];
        }
        __syncthreads();
        for (int e = e0 + tid; e < e1; e += 256) {
            int t = dst[e];
            int b = ((unsigned)t) >> 6;
            int pos = atomicAdd(&hist[b], 1);
            if (pos < (b + 1) * BCAP)   // overflow clamp (16-sigma margin)
                pairs[pos] = (unsigned)src[e] | ((unsigned)(t & 63) << 17);
        }
        return;
    }

    // ---------------- gemm1 path: split-bf16 MFMA, no LDS -----------------
    int tile = 4 * g + r5;
    if (tile >= GB) return;
    int nblk = tile * 64;

    int l  = tid & 63, wv = tid >> 6;   // lane, wave(0..3)
    int la = l & 15,   g4 = l >> 4;     // col-within-16, k-group
    int arow = nblk + wv * 16 + la;     // A row for this lane
    bool rowOK = (arow < N);

    // A fragments from global (16 rows x 128B contiguous per k-half)
    BU ahi[2], alo[2];
    #pragma unroll
    for (int kf = 0; kf < 2; ++kf) {
        float xv[8];
        if (rowOK) {
            const float* xp = &x[(size_t)arow * 64 + kf * 32 + g4 * 8];
            float4 p0 = *(const float4*)xp;
            float4 p1 = *(const float4*)(xp + 4);
            xv[0] = p0.x; xv[1] = p0.y; xv[2] = p0.z; xv[3] = p0.w;
            xv[4] = p1.x; xv[5] = p1.y; xv[6] = p1.z; xv[7] = p1.w;
        } else {
            #pragma unroll
            for (int e = 0; e < 8; ++e) xv[e] = 0.0f;
        }
        #pragma unroll
        for (int e = 0; e < 8; ++e) {
            unsigned short h = f2bf(xv[e]);
            ahi[kf].u[e] = h;
            alo[kf].u[e] = f2bf(xv[e] - bf2f(h));
        }
    }

    unsigned short* u16 = (unsigned short*)u16b;

    #pragma unroll
    for (int pass = 0; pass < 2; ++pass) {
        #pragma unroll
        for (int nf = 0; nf < 4; ++nf) {
            int n0 = nf * 16;
            f32x4 acc = {0.f, 0.f, 0.f, 0.f};
            #pragma unroll
            for (int kf = 0; kf < 2; ++kf) {
                int q2 = ((pass * 4 + nf) * 2 + kf) * 2;
                bf16x8 bhi = *(const bf16x8*)&Wf[(q2 + 0) * 512 + l * 8];
                bf16x8 blo = *(const bf16x8*)&Wf[(q2 + 1) * 512 + l * 8];
                acc = __builtin_amdgcn_mfma_f32_16x16x32_bf16(ahi[kf].v, bhi, acc, 0, 0, 0);
                acc = __builtin_amdgcn_mfma_f32_16x16x32_bf16(alo[kf].v, bhi, acc, 0, 0, 0);
                acc = __builtin_amdgcn_mfma_f32_16x16x32_bf16(ahi[kf].v, blo, acc, 0, 0, 0);
            }
            // D: col = la, row = g4*4 + r  (m89-verified layout)
            if (pass == 0) {
                #pragma unroll
                for (int rr = 0; rr < 4; ++rr) {
                    int nd = nblk + wv * 16 + g4 * 4 + rr;
                    if (nd < N)
                        u16[(size_t)nd * 64 + n0 + la] = f2bf(acc[rr]);
                }
            } else {
                float bb = b1[n0 + la];
                #pragma unroll
                for (int rr = 0; rr < 4; ++rr) {
                    int nd = nblk + wv * 16 + g4 * 4 + rr;
                    if (nd < N)
                        v[(size_t)nd * 64 + n0 + la] = acc[rr] + bb;
                }
            }
        }
    }
}

// --- M2: local-CSR (persisted) + agg1 + gemm2(MFMA). Block = 64-node bucket.
// CSR: LDS histogram -> 1-wave scan -> LDS-cursor fill; adj+nodeOff -> global.
// Phase A: 16 half-waves x 4 nodes register serial-walk gather (unroll 8);
//          h written packed (bf16hi|bf16lo) per uint into sHu.
// Phase B: 64x64 split-bf16 MFMA: cols 0..31 -> P16b(bf16), 32..63 -> Q+b2.
__global__ __launch_bounds__(512) void k_m2(
    const unsigned* __restrict__ pairs, const int* __restrict__ gcnt,
    const unsigned* __restrict__ u16b, const float* __restrict__ v,
    const unsigned short* __restrict__ Wf, const float* __restrict__ b2,
    unsigned* __restrict__ P16b, float* __restrict__ Qout,
    int2* __restrict__ nodeOff, int* __restrict__ adjG, int N)
{
    __shared__ unsigned sHu[64 * 76]; // 19456B packed h tile, stride 76
    __shared__ int   sAdj[BCAP];      // 6144B
    __shared__ int   sOff[65];
    __shared__ int   sCur[64];
    int tid = threadIdx.x;
    int b = blockIdx.x;
    int nodeBase = b * 64;
    int base = b * BCAP;
    int count = min(gcnt[b], BCAP);
    const unsigned* pp = pairs + (size_t)b * BCAP;

    if (tid < 64) sCur[tid] = 0;
    __syncthreads();

    // ---- local CSR: histogram -> scan -> fill ----
    for (int j = tid; j < count; j += 512)
        atomicAdd(&sCur[(pp[j] >> 17) & 63], 1);
    __syncthreads();
    if (tid < 64) {
        int c = sCur[tid];
        int incl = c;
        #pragma unroll
        for (int off = 1; off < 64; off <<= 1) {
            int t = __shfl_up(incl, off);
            if (tid >= off) incl += t;
        }
        sOff[tid] = incl - c;
        if (tid == 63) sOff[64] = incl;
    }
    __syncthreads();
    if (tid < 64) {
        sCur[tid] = sOff[tid];
        int node = nodeBase + tid;
        if (node < N)
            nodeOff[node] = make_int2(base + sOff[tid], sOff[tid + 1] - sOff[tid]);
    }
    __syncthreads();
    for (int j = tid; j < count; j += 512) {
        unsigned e = pp[j];
        int pos = atomicAdd(&sCur[(e >> 17) & 63], 1);
        sAdj[pos] = (int)(e & 0x1FFFFu);
    }
    __syncthreads();
    // persist adj for k_a2 (coalesced burst)
    for (int j = tid; j < count; j += 512) adjG[base + j] = sAdj[j];

    // ---- Phase A: 16 half-waves x 4 nodes, register serial walk ----
    int hw = tid >> 5, lane = tid & 31;
    for (int r = 0; r < 4; ++r) {
        int nl = hw * 4 + r;
        int node = nodeBase + nl;
        float h0 = 0.0f, h1v = 0.0f;
        if (node < N) {
            int beg = sOff[nl], end = sOff[nl + 1];
            float lo[8] = {0,0,0,0,0,0,0,0}, hi[8] = {0,0,0,0,0,0,0,0};
            int i = beg;
            for (; i + 8 <= end; i += 8) {
                int s[8];
                #pragma unroll
                for (int j = 0; j < 8; ++j) s[j] = sAdj[i + j];
                #pragma unroll
                for (int j = 0; j < 8; ++j) {
                    unsigned w = u16b[(size_t)s[j] * 32 + lane];
                    lo[j] += bflo(w); hi[j] += bfhi(w);
                }
            }
            for (; i < end; ++i) {
                unsigned w = u16b[(size_t)sAdj[i] * 32 + lane];
                lo[0] += bflo(w); hi[0] += bfhi(w);
            }
            float mlo = ((lo[0]+lo[1])+(lo[2]+lo[3])) + ((lo[4]+lo[5])+(lo[6]+lo[7]));
            float mhi = ((hi[0]+hi[1])+(hi[2]+hi[3])) + ((hi[4]+hi[5])+(hi[6]+hi[7]));
            int deg = end - beg;
            float invd = (deg > 0) ? 1.0f / (float)deg : 1.0f;
            float2 vv = ((const float2*)v)[(size_t)node * 32 + lane];
            h0  = fmaxf(mlo * invd + vv.x, 0.0f);
            h1v = fmaxf(mhi * invd + vv.y, 0.0f);
        }
        // features 2*lane, 2*lane+1 packed hi|lo
        *(uint2*)&sHu[nl * 76 + 2 * lane] = make_uint2(packhl(h0), packhl(h1v));
    }
    __syncthreads();

    // ---- Phase B: 64x64 split-bf16 MFMA (8 waves x 2 n-tiles) ----
    int w = tid >> 6, l = tid & 63;
    int la = l & 15, g4 = l >> 4;
    int mtile = w & 3, nt2 = (w >> 2) * 2;   // n-tiles nt2, nt2+1

    BU ahi[2], alo[2];
    #pragma unroll
    for (int kf = 0; kf < 2; ++kf) {
        const unsigned* hp = &sHu[(mtile * 16 + la) * 76 + kf * 32 + g4 * 8];
        uint4 a0 = *(const uint4*)hp;
        uint4 a1 = *(const uint4*)(hp + 4);
        unsigned wv8[8] = {a0.x, a0.y, a0.z, a0.w, a1.x, a1.y, a1.z, a1.w};
        #pragma unroll
        for (int e = 0; e < 8; ++e) {
            ahi[kf].u[e] = (unsigned short)wv8[e];
            alo[kf].u[e] = (unsigned short)(wv8[e] >> 16);
        }
    }

    unsigned short* Pus = (unsigned short*)P16b;
    #pragma unroll
    for (int j = 0; j < 2; ++j) {
        int ntile = nt2 + j;
        f32x4 acc = {0.f, 0.f, 0.f, 0.f};
        #pragma unroll
        for (int kf = 0; kf < 2; ++kf) {
            const unsigned short* Wq = Wf + (size_t)(32 + (ntile * 2 + kf) * 2) * 512;
            bf16x8 bhi = *(const bf16x8*)&Wq[l * 8];
            bf16x8 blo = *(const bf16x8*)&Wq[512 + l * 8];
            acc = __builtin_amdgcn_mfma_f32_16x16x32_bf16(ahi[kf].v, bhi, acc, 0, 0, 0);
            acc = __builtin_amdgcn_mfma_f32_16x16x32_bf16(alo[kf].v, bhi, acc, 0, 0, 0);
            acc = __builtin_amdgcn_mfma_f32_16x16x32_bf16(ahi[kf].v, blo, acc, 0, 0, 0);
        }
        int col = ntile * 16 + la;
        if (col < 32) {
            #pragma unroll
            for (int rr = 0; rr < 4; ++rr) {
                int node = nodeBase + mtile * 16 + g4 * 4 + rr;
                if (node < N)
                    Pus[(size_t)node * 32 + col] = f2bf(acc[rr]);
            }
        } else {
            float bb = b2[col - 32];
            #pragma unroll
            for (int rr = 0; rr < 4; ++rr) {
                int node = nodeBase + mtile * 16 + g4 * 4 + rr;
                if (node < N)
                    Qout[(size_t)node * 32 + (col - 32)] = acc[rr] + bb;
            }
        }
    }
}

// --- A2 (round-8 verbatim): h = mean(P[neigh]) + Q -> out_h ; trust head ----
// 16 lanes per node; 64B fully-coalesced edge gather, 8-deep MLP.
__global__ __launch_bounds__(256) void k_a2(
    const int2* __restrict__ nodeOff, const int* __restrict__ adj,
    const unsigned* __restrict__ P16b, const float* __restrict__ Q,
    const float* __restrict__ Wt1, const float* __restrict__ bt1,
    const float* __restrict__ Wt2, const float* __restrict__ bt2,
    float* __restrict__ out_h, float* __restrict__ out_trust, int N)
{
    __shared__ float sWt1[32 * 16];
    __shared__ float sWt2[16];
    for (int i = threadIdx.x; i < 512; i += 256) sWt1[i] = Wt1[i];
    if (threadIdx.x < 16) sWt2[threadIdx.x] = Wt2[threadIdx.x];
    __syncthreads();

    int n = blockIdx.x * 16 + (threadIdx.x >> 4);
    int lane = threadIdx.x & 15;
    if (n >= N) return;

    int2 od = nodeOff[n];
    int beg = od.x, end = od.x + od.y;
    float lo[8] = {0,0,0,0,0,0,0,0}, hi[8] = {0,0,0,0,0,0,0,0};
    int i = beg;
    for (; i + 8 <= end; i += 8) {
        int s[8];
        #pragma unroll
        for (int j = 0; j < 8; ++j) s[j] = adj[i + j];
        #pragma unroll
        for (int j = 0; j < 8; ++j) {
            unsigned w = P16b[(size_t)s[j] * 16 + lane];
            lo[j] += bflo(w); hi[j] += bfhi(w);
        }
    }
    for (; i < end; ++i) {
        unsigned w = P16b[(size_t)adj[i] * 16 + lane];
        lo[0] += bflo(w); hi[0] += bfhi(w);
    }
    float invd = (od.y > 0) ? 1.0f / (float)od.y : 1.0f;
    float mlo = (((lo[0]+lo[1])+(lo[2]+lo[3])) + ((lo[4]+lo[5])+(lo[6]+lo[7]))) * invd;
    float mhi = (((hi[0]+hi[1])+(hi[2]+hi[3])) + ((hi[4]+hi[5])+(hi[6]+hi[7]))) * invd;

    float2 qv = ((const float2*)Q)[(size_t)n * 16 + lane];
    float hx = mlo + qv.x;
    float hy = mhi + qv.y;

    ((float2*)out_h)[(size_t)n * 16 + lane] = make_float2(hx, hy);

    float t = bt1[lane];
    #pragma unroll
    for (int k = 0; k < 16; ++k) {
        float hlo = __shfl(hx, k, 16);
        float hhi = __shfl(hy, k, 16);
        t += hlo * sWt1[(2 * k) * 16 + lane] + hhi * sWt1[(2 * k + 1) * 16 + lane];
    }
    t = fmaxf(t, 0.0f);
    float z = t * sWt2[lane];
    z += __shfl_xor(z, 1);
    z += __shfl_xor(z, 2);
    z += __shfl_xor(z, 4);
    z += __shfl_xor(z, 8);
    if (lane == 0) out_trust[n] = 1.0f / (1.0f + expf(-(z + bt2[0])));
}

// ---------------------------------------------------------------------------

extern "C" void kernel_launch(void* const* d_in, const int* in_sizes, int n_in,
                              void* d_out, int out_size, void* d_ws, size_t ws_size,
                              hipStream_t stream)
{
    const float* x   = (const float*)d_in[0];
    const int*   ei  = (const int*)d_in[1];
    const float* Wl1 = (const float*)d_in[2];
    const float* Wr1 = (const float*)d_in[3];
    const float* b1  = (const float*)d_in[4];
    const float* Wl2 = (const float*)d_in[5];
    const float* Wr2 = (const float*)d_in[6];
    const float* b2  = (const float*)d_in[7];
    const float* Wt1 = (const float*)d_in[8];
    const float* bt1 = (const float*)d_in[9];
    const float* Wt2 = (const float*)d_in[10];
    const float* bt2 = (const float*)d_in[11];

    const int N = in_sizes[0] / 64;   // 100000
    const int E = in_sizes[1] / 2;    // 1600000
    const int* src = ei;
    const int* dst = ei + E;

    // Workspace layout (all segments 64B-aligned)
    unsigned* pairs  = (unsigned*)d_ws;                        // NBUCK*BCAP (~9.6MB)
    unsigned* u16b   = pairs + (size_t)NBUCK * BCAP;           // N*32 (bf16 x2)
    float*    v      = (float*)(u16b + (size_t)N * 32);        // N*64
    unsigned* P16b   = (unsigned*)(v + (size_t)N * 64);        // N*16 (bf16 x2)
    float*    Q      = (float*)(P16b + (size_t)N * 16);        // N*32
    int2*     nodeOff= (int2*)(Q + (size_t)N * 32);            // N
    int*      adj    = (int*)(nodeOff + N);                    // NBUCK*BCAP
    int*      gcnt   = adj + (size_t)NBUCK * BCAP;             // 2048 (1563 used)
    unsigned short* Wf = (unsigned short*)(gcnt + 2048);       // 48 planes x 512
    // total ~78 MB

    hipMemsetAsync(gcnt, 0, 2048 * sizeof(int), stream);

    k_w<<<1, 256, 0, stream>>>(Wl1, Wr1, Wl2, Wr2, Wf);

    const int GB  = (N + 63) / 64;               // 1563 gemm1 tiles
    const int BKB = (E + BKCHUNK - 1) / BKCHUNK; // 391 bucket chunks
    int grp = (GB + 3) / 4 > BKB ? (GB + 3) / 4 : BKB;   // 391
    k_m1<<<5 * grp, 256, 0, stream>>>(x, Wf, b1, u16b, v,
                                      src, dst, gcnt, pairs, N, E, GB, BKB);
    k_m2<<<NBUCK, 512, 0, stream>>>(pairs, gcnt, u16b, v, Wf, b2,
                                    P16b, Q, nodeOff, adj, N);

    float* out_h     = (float*)d_out;
    float* out_trust = out_h + (size_t)N * 32;
    k_a2<<<(N + 15) / 16, 256, 0, stream>>>(nodeOff, adj, P16b, Q,
                                            Wt1, bt1, Wt2, bt2,
                                            out_h, out_trust, N);
}